// Round 4
// baseline (285.737 us; speedup 1.0000x reference)
//
#include <hip/hip_runtime.h>

// pos[b][f][i][j] = row_embed[Z(i,j)][f],  Z = max(|32-j| + |32-i| - 1, 0)
// b=32, F=512, h=w=64. Output fp32, 256 MiB -> pure write-BW bound.
//
// R1 lesson: 32-way batch fan-out per wave broke the linear write stream (~1 TB/s).
// R2 lesson: one block per (b,f), contiguous 16 KB/block -> total 255.7 us.
// R3 lesson: 8x fewer blocks, 32 contiguous 1KB stores/wave -> NEUTRAL (258.1).
//   Block/launch overhead theory falsified.
// R4 lesson: nontemporal stores -> NEUTRAL (266.3, = R3 after clock scaling;
//   fills were 3% slower that run too). Dirty-LLC eviction theory falsified.
// R5 DIAGNOSTIC: three structurally different kernels are time-invariant. Either
//   (a) the kernel really runs at ~2.8 TB/s (~95 us) for a reason not yet found, or
//   (b) the kernel is already at the ~6.5 TB/s write roofline (~45 us) and the
//       residual is fixed harness overhead (the ~13 tiny reset dispatches per
//       iteration visible in the Dispatch_Id strides).
//   Discriminator: write the output TWICE (idempotent, correctness unchanged).
//   (a) predicts dur_us ~350 and pe_kernel visible in top-5 (~185 us);
//   (b) predicts dur_us ~300-310 and pe_kernel still hidden (<163 us).
//   Structure otherwise identical to R3 (plain float4 stores).

#define NUM_POS_FEATS 512
#define H 64
#define W 64
#define B 32
#define GRID 2048
#define IMGS_PER_BLOCK ((B * NUM_POS_FEATS) / GRID)   // 8

__global__ __launch_bounds__(256) void pe_kernel(const float* __restrict__ row_embed,
                                                 float* __restrict__ out) {
    __shared__ float col[64];   // row_embed[z][f] for z in [0,64)

    const int g   = blockIdx.x;                 // 0..2047
    const int f   = g & (NUM_POS_FEATS - 1);    // invariant across this block's images
    const int tid = threadIdx.x;

    if (tid < 64) {
        col[tid] = row_embed[tid * NUM_POS_FEATS + f];
    }
    __syncthreads();

    // Compute this thread's 16 output values ONCE (image is independent of b).
    float4 v[4];
#pragma unroll
    for (int k = 0; k < 4; ++k) {
        const int idx = k * 256 + tid;          // quad index 0..1023 within image
        const int i   = idx >> 4;               // row
        const int j4  = (idx & 15) << 2;        // quad start column
        const int di  = abs(32 - i);

        int z0 = di + abs(32 - (j4 + 0)) - 1; v[k].x = col[z0 < 0 ? 0 : z0];
        int z1 = di + abs(32 - (j4 + 1)) - 1; v[k].y = col[z1 < 0 ? 0 : z1];
        int z2 = di + abs(32 - (j4 + 2)) - 1; v[k].z = col[z2 < 0 ? 0 : z2];
        int z3 = di + abs(32 - (j4 + 3)) - 1; v[k].w = col[z3 < 0 ? 0 : z3];
    }

    const size_t step = (size_t)GRID * (H * W / 4);     // 2048 * 1024 quads = 32 MiB

    // DIAGNOSTIC: two full write passes. The asm memory clobber between reps
    // forces the first pass's stores to actually issue (no dedup of identical
    // stores to the same address).
#pragma unroll 1
    for (int rep = 0; rep < 2; ++rep) {
        float4* o = reinterpret_cast<float4*>(out) + (size_t)g * (H * W / 4);
#pragma unroll
        for (int t = 0; t < IMGS_PER_BLOCK; ++t) {
#pragma unroll
            for (int k = 0; k < 4; ++k) {
                o[k * 256 + tid] = v[k];        // contiguous 1 KB per wave per store
            }
            o += step;
        }
        asm volatile("" ::: "memory");
    }
}

extern "C" void kernel_launch(void* const* d_in, const int* in_sizes, int n_in,
                              void* d_out, int out_size, void* d_ws, size_t ws_size,
                              hipStream_t stream) {
    // d_in[0] = x (32,3,64,64) fp32 — unused (shape only)
    // d_in[1] = row_embed (64,512) fp32
    const float* row_embed = (const float*)d_in[1];
    float* out = (float*)d_out;

    pe_kernel<<<GRID, 256, 0, stream>>>(row_embed, out);
}

// Round 5
// 256.640 us; speedup vs baseline: 1.1134x; 1.1134x over previous
//
#include <hip/hip_runtime.h>
#include <hip/hip_bf16.h>

// pos[b][f][i][j] = row_embed[Z(i,j)][f],  Z = max(|32-j| + |32-i| - 1, 0)
// b=32, F=512, h=w=64. Output fp32, 256 MiB -> pure write-BW bound.
//
// Session ledger:
// R1: 32-way batch fan-out per wave (stores 8 MiB apart) -> ~1 TB/s. Linear
//     write stream matters.
// R2 (THIS KERNEL): one block per (b,f) image, 16 KB contiguous per block,
//     consecutive blocks -> consecutive memory. 255.7 us total. BEST.
// R3: 2048 blocks, 8 images/block, 32 contiguous 1KB stores/wave, one
//     LDS-stage+barrier -> 258.1 us. NEUTRAL: block/launch overhead theory
//     falsified.
// R4: nontemporal stores (global_store_dwordx4 nt) -> neutral after clock
//     scaling. Dirty-LLC-eviction theory falsified.
// R5: DIAGNOSTIC double-write pass -> +27.7 us for an extra 256 MiB pass
//     (9.3 TB/s marginal, LLC-absorbed). Store-issue path has 3x headroom;
//     kernel-side scheduling is not the limiter.
//
// Conclusion (fits all rounds): kernel itself runs at ~41-45 us = 256 MiB at
// the ~6.5 TB/s write ceiling the harness's own 1 GiB re-poison fill
// demonstrates (162 us, WRITE_SIZE fully drained in-window). The remaining
// dur_us is harness-fixed: ~162 us poison fill + ~50 us of tiny reset graph
// nodes (~13-15 Dispatch_Id strides/iteration). Structural floor
// 162 + ~50 + 41 = ~253 us ~= best observed 255.7. Three structurally
// different store schedules + one cache-policy change all within noise
// confirms the kernel term is already sub-dominant and at roofline.

#define NUM_POS_FEATS 512
#define H 64
#define W 64
#define B 32

__global__ __launch_bounds__(256) void pe_kernel(const float* __restrict__ row_embed,
                                                 float* __restrict__ out) {
    __shared__ float col[64];   // row_embed[z][f] for z in [0,64)

    const int bf  = blockIdx.x;        // b*512 + f, 0..16383
    const int f   = bf & (NUM_POS_FEATS - 1);
    const int tid = threadIdx.x;

    if (tid < 64) {
        col[tid] = row_embed[tid * NUM_POS_FEATS + f];
    }
    __syncthreads();

    // This block's image: 64*64 = 4096 floats = 1024 float4 quads.
    float4* o = reinterpret_cast<float4*>(out + (size_t)bf * (H * W));

#pragma unroll
    for (int k = 0; k < 4; ++k) {
        const int idx = k * 256 + tid;        // quad index 0..1023
        const int i   = idx >> 4;             // row
        const int j4  = (idx & 15) << 2;      // quad start column
        const int di  = abs(32 - i);

        float4 v;
        {
            int z = di + abs(32 - (j4 + 0)) - 1; v.x = col[z < 0 ? 0 : z];
        }
        {
            int z = di + abs(32 - (j4 + 1)) - 1; v.y = col[z < 0 ? 0 : z];
        }
        {
            int z = di + abs(32 - (j4 + 2)) - 1; v.z = col[z < 0 ? 0 : z];
        }
        {
            int z = di + abs(32 - (j4 + 3)) - 1; v.w = col[z < 0 ? 0 : z];
        }
        o[idx] = v;
    }
}

extern "C" void kernel_launch(void* const* d_in, const int* in_sizes, int n_in,
                              void* d_out, int out_size, void* d_ws, size_t ws_size,
                              hipStream_t stream) {
    // d_in[0] = x (32,3,64,64) fp32 — unused (shape only)
    // d_in[1] = row_embed (64,512) fp32
    const float* row_embed = (const float*)d_in[1];
    float* out = (float*)d_out;

    const int grid = B * NUM_POS_FEATS;   // 16384 blocks, one per (b,f) image
    pe_kernel<<<grid, 256, 0, stream>>>(row_embed, out);
}